// Round 1
// baseline (6340.883 us; speedup 1.0000x reference)
//
#include <hip/hip_runtime.h>
#include <hip/hip_bf16.h>

#define NBATCH 16
#define NBR    8
#define CIN    3
#define HIN    224
#define WIN    224
#define COUT   64
#define OHH    112
#define OWW    112
#define PHH    56
#define PWW    56
#define CNT    (NBATCH*OHH*OWW)   // 200704 elements per (b,co) channel

// ---------------- Kernel 1: conv(7x7,s2,p3) + bf16 y store + BN stats ----------------
// grid.x = NBATCH*OHH (one conv output row per block), block = 512 (8 waves)
// wave w handles co in [8w, 8w+8); lanes = ow (0..63) + second chunk (64..111)
__global__ __launch_bounds__(512)
void conv_bn_stats(const float* __restrict__ x, const float* __restrict__ w,
                   __hip_bfloat16* __restrict__ y, float* __restrict__ stats, int b)
{
    __shared__ float xs[CIN][7][232];   // 7 input rows x 230 cols (zero-padded), +2 pad

    int bid = blockIdx.x;
    int oh  = bid % OHH;
    int n   = bid / OHH;

    const float* xb = x + ((size_t)(n*NBR + b))*CIN*HIN*WIN;
    int ihb = oh*2 - 3;
    for (int idx = threadIdx.x; idx < CIN*7*230; idx += 512) {
        int ci = idx / (7*230);
        int r  = idx - ci*(7*230);
        int kh = r / 230;
        int c  = r - kh*230;
        int ih = ihb + kh, iw = c - 3;
        float v = 0.f;
        if ((unsigned)ih < (unsigned)HIN && (unsigned)iw < (unsigned)WIN)
            v = xb[(ci*HIN + ih)*WIN + iw];
        xs[ci][kh][c] = v;
    }
    __syncthreads();

    int wid  = __builtin_amdgcn_readfirstlane(threadIdx.x >> 6);
    int lane = threadIdx.x & 63;
    int co0  = wid * 8;
    const float* wb = w + ((size_t)b*COUT + co0)*147;   // [co][ci][kh][kw], co stride 147

    float acc0[8], acc1[8];
    #pragma unroll
    for (int cc = 0; cc < 8; ++cc) { acc0[cc] = 0.f; acc1[cc] = 0.f; }
    int ow1 = lane + 64;

    for (int ci = 0; ci < CIN; ++ci)
        for (int kh = 0; kh < 7; ++kh) {
            // weights are wave-uniform -> scalar loads
            float wr[8][7];
            #pragma unroll
            for (int cc = 0; cc < 8; ++cc)
                #pragma unroll
                for (int kw = 0; kw < 7; ++kw)
                    wr[cc][kw] = wb[cc*147 + ci*49 + kh*7 + kw];
            const float* xr = &xs[ci][kh][0];
            #pragma unroll
            for (int kw = 0; kw < 7; ++kw) {
                float xv0 = xr[lane*2 + kw];
                float xv1 = 0.f;
                if (ow1 < OWW) xv1 = xr[ow1*2 + kw];
                #pragma unroll
                for (int cc = 0; cc < 8; ++cc) {
                    acc0[cc] = fmaf(xv0, wr[cc][kw], acc0[cc]);
                    acc1[cc] = fmaf(xv1, wr[cc][kw], acc1[cc]);
                }
            }
        }

    // store y (bf16), layout per-b: [n][co][oh][ow]
    if (y) {
        __hip_bfloat16* yb = y + ((size_t)n*COUT + co0)*(OHH*OWW) + (size_t)oh*OWW;
        #pragma unroll
        for (int cc = 0; cc < 8; ++cc) {
            __hip_bfloat16* yr = yb + (size_t)cc*(OHH*OWW);
            yr[lane] = __float2bfloat16(acc0[cc]);
            if (ow1 < OWW) yr[ow1] = __float2bfloat16(acc1[cc]);
        }
    }

    // per-channel sum / sumsq (inactive-chunk lanes hold 0 -> safe to include)
    #pragma unroll
    for (int cc = 0; cc < 8; ++cc) {
        float s = acc0[cc] + acc1[cc];
        float q = acc0[cc]*acc0[cc] + acc1[cc]*acc1[cc];
        #pragma unroll
        for (int off = 32; off; off >>= 1) {
            s += __shfl_xor(s, off);
            q += __shfl_xor(q, off);
        }
        if (lane == 0) {
            atomicAdd(&stats[(co0+cc)*2 + 0], s);
            atomicAdd(&stats[(co0+cc)*2 + 1], q);
        }
    }
}

// ---------------- Kernel 2: BN-affine + ReLU + maxpool3x3 s2 p1 ----------------
// grid.x = NBATCH*COUT*PHH*PWW/256, block = 256; one output pixel per thread
__global__ __launch_bounds__(256)
void pool_affine(const __hip_bfloat16* __restrict__ y, const float* __restrict__ stats,
                 const float* __restrict__ gamma, const float* __restrict__ beta,
                 float* __restrict__ out, int b)
{
    int idx = blockIdx.x*256 + threadIdx.x;
    int pw = idx % PWW;
    int t  = idx / PWW;
    int ph = t % PHH; t /= PHH;
    int co = t % COUT;
    int n  = t / COUT;

    float mean = stats[co*2 + 0] * (1.f/CNT);
    float var  = stats[co*2 + 1] * (1.f/CNT) - mean*mean;
    float inv  = rsqrtf(var + 1e-5f);
    float scale = gamma[co]*inv;
    float shift = beta[co] - mean*scale;

    const __hip_bfloat16* yp = y + ((size_t)n*COUT + co)*(OHH*OWW);
    float m = -1e30f;
    int h0 = 2*ph - 1, w0 = 2*pw - 1;
    #pragma unroll
    for (int dh = 0; dh < 3; ++dh) {
        int ih = h0 + dh;
        if ((unsigned)ih < (unsigned)OHH) {
            const __hip_bfloat16* row = yp + ih*OWW;
            #pragma unroll
            for (int dw = 0; dw < 3; ++dw) {
                int iw = w0 + dw;
                if ((unsigned)iw < (unsigned)OWW) {
                    float v = __bfloat162float(row[iw]);
                    m = fmaxf(m, fmaf(v, scale, shift));
                }
            }
        }
    }
    out[(((size_t)n*NBR + b)*COUT + co)*(PHH*PWW) + (size_t)ph*PWW + pw] = fmaxf(m, 0.f);
}

// ---------------- Fallback (tiny workspace): recompute conv per pooled pixel ----------------
__global__ __launch_bounds__(256)
void pool_recompute(const float* __restrict__ x, const float* __restrict__ w,
                    const float* __restrict__ stats, const float* __restrict__ gamma,
                    const float* __restrict__ beta, float* __restrict__ out, int b)
{
    int idx = blockIdx.x*256 + threadIdx.x;
    int pw = idx % PWW;
    int t  = idx / PWW;
    int ph = t % PHH; t /= PHH;
    int co = t % COUT;
    int n  = t / COUT;

    float mean = stats[co*2 + 0] * (1.f/CNT);
    float var  = stats[co*2 + 1] * (1.f/CNT) - mean*mean;
    float inv  = rsqrtf(var + 1e-5f);
    float scale = gamma[co]*inv;
    float shift = beta[co] - mean*scale;

    const float* xb = x + ((size_t)(n*NBR + b))*CIN*HIN*WIN;
    const float* wb = w + ((size_t)b*COUT + co)*147;

    float m = -1e30f;
    for (int dh = 0; dh < 3; ++dh) {
        int oh = 2*ph - 1 + dh;
        if ((unsigned)oh >= (unsigned)OHH) continue;
        for (int dw = 0; dw < 3; ++dw) {
            int ow = 2*pw - 1 + dw;
            if ((unsigned)ow >= (unsigned)OWW) continue;
            float a = 0.f;
            for (int ci = 0; ci < CIN; ++ci)
                for (int kh = 0; kh < 7; ++kh) {
                    int ih = oh*2 - 3 + kh;
                    if ((unsigned)ih >= (unsigned)HIN) continue;
                    for (int kw = 0; kw < 7; ++kw) {
                        int iw = ow*2 - 3 + kw;
                        if ((unsigned)iw >= (unsigned)WIN) continue;
                        a = fmaf(xb[(ci*HIN + ih)*WIN + iw], wb[ci*49 + kh*7 + kw], a);
                    }
                }
            m = fmaxf(m, fmaf(a, scale, shift));
        }
    }
    out[(((size_t)n*NBR + b)*COUT + co)*(PHH*PWW) + (size_t)ph*PWW + pw] = fmaxf(m, 0.f);
}

extern "C" void kernel_launch(void* const* d_in, const int* in_sizes, int n_in,
                              void* d_out, int out_size, void* d_ws, size_t ws_size,
                              hipStream_t stream) {
    const float* x     = (const float*)d_in[0];
    const float* w     = (const float*)d_in[1];
    const float* gamma = (const float*)d_in[2];
    const float* beta  = (const float*)d_in[3];
    float* out = (float*)d_out;

    const size_t statsBytes = 512 * 2 * sizeof(float);                  // 4 KB
    const size_t yBytes = (size_t)NBATCH*COUT*OHH*OWW*sizeof(__hip_bfloat16); // 25.7 MB (per-b, reused)
    float* stats = (float*)d_ws;
    __hip_bfloat16* y = (__hip_bfloat16*)((char*)d_ws + 4096);
    bool fits = ws_size >= 4096 + yBytes;

    hipMemsetAsync(d_ws, 0, statsBytes, stream);

    const int convGrid = NBATCH * OHH;                    // 1792
    const int poolGrid = NBATCH * COUT * PHH * PWW / 256; // 12544

    for (int b = 0; b < NBR; ++b) {
        float* statsB = stats + b*128;
        conv_bn_stats<<<convGrid, 512, 0, stream>>>(x, w, fits ? y : nullptr, statsB, b);
        if (fits)
            pool_affine<<<poolGrid, 256, 0, stream>>>(y, statsB, gamma + b*COUT, beta + b*COUT, out, b);
        else
            pool_recompute<<<poolGrid, 256, 0, stream>>>(x, w, statsB, gamma + b*COUT, beta + b*COUT, out, b);
    }
}

// Round 3
// 1000.991 us; speedup vs baseline: 6.3346x; 6.3346x over previous
//
#include <hip/hip_runtime.h>
#include <hip/hip_bf16.h>

#define NBATCH 16
#define NBR    8
#define CIN    3
#define HIN    224
#define WIN    224
#define COUT   64
#define OHH    112
#define OWW    112
#define PHH    56
#define PWW    56
#define CNT    (NBATCH*OHH*OWW)   // 200704 elements per (b,co) channel

// ================= fast path =================
// Weight transpose: wT[k][co], k = (ci*7+kh)*7+kw  (147 x 64 fp32)
__global__ __launch_bounds__(256)
void wtrans(const float* __restrict__ w, float* __restrict__ wT, int b)
{
    int i = blockIdx.x*256 + threadIdx.x;
    if (i < 147*64) {
        int co = i & 63, k = i >> 6;
        wT[i] = w[((size_t)b*COUT + co)*147 + k];
    }
}

// One chunk: 14 output px, x window = 33 uniform floats (scalar loads), 98 FMA.
template<bool CHK>
__device__ __forceinline__ void chunk(const float* __restrict__ xr,
                                      const float wv[7], float* __restrict__ acc,
                                      int owb)
{
    float xu[33];
    #pragma unroll
    for (int j = 0; j < 33; ++j) {
        int iw = 2*owb - 3 + j;
        if (CHK)
            xu[j] = ((unsigned)iw < (unsigned)WIN) ? xr[iw] : 0.f;
        else
            xu[j] = xr[iw];
    }
    #pragma unroll
    for (int px = 0; px < 14; ++px)
        #pragma unroll
        for (int kw = 0; kw < 7; ++kw)
            acc[px] = fmaf(xu[2*px + kw], wv[kw], acc[px]);
}

// conv(7x7,s2,p3): lane = co. Each wave computes one 56-px half-row for all 64 co.
// grid = 3584 waves / 4 per block = 896 blocks, block = 256.
// y layout: [n][oh][ow][co] bf16 (coalesced store AND coalesced pool load).
__global__ __launch_bounds__(256)
void conv_fast(const float* __restrict__ x, const float* __restrict__ wT,
               __hip_bfloat16* __restrict__ y, float* __restrict__ stats, int b)
{
    int wid  = __builtin_amdgcn_readfirstlane(threadIdx.x >> 6);
    int lane = threadIdx.x & 63;
    int wg = blockIdx.x*4 + wid;          // 0..3583
    int h  = wg & 1;
    int oh = (wg >> 1) % OHH;
    int n  = wg / (2*OHH);

    const float* xb = x + ((size_t)(n*NBR + b))*CIN*HIN*WIN;

    float acc[56];
    #pragma unroll
    for (int i = 0; i < 56; ++i) acc[i] = 0.f;

    #pragma unroll 1
    for (int ci = 0; ci < CIN; ++ci) {
        #pragma unroll 1
        for (int kh = 0; kh < 7; ++kh) {
            int ihr = 2*oh - 3 + kh;
            bool ok = (unsigned)ihr < (unsigned)HIN;
            int ih = ok ? ihr : 0;

            float wv[7];
            #pragma unroll
            for (int kw = 0; kw < 7; ++kw)
                wv[kw] = wT[((ci*7 + kh)*7 + kw)*64 + lane];
            if (!ok) {
                #pragma unroll
                for (int kw = 0; kw < 7; ++kw) wv[kw] = 0.f;
            }

            int rowoff = __builtin_amdgcn_readfirstlane((ci*HIN + ih)*WIN);
            const float* xr = xb + rowoff;

            if (h == 0) {
                chunk<true >(xr, wv, acc + 0,   0);
                chunk<false>(xr, wv, acc + 14, 14);
                chunk<false>(xr, wv, acc + 28, 28);
                chunk<false>(xr, wv, acc + 42, 42);
            } else {
                chunk<false>(xr, wv, acc + 0,  56);
                chunk<false>(xr, wv, acc + 14, 70);
                chunk<false>(xr, wv, acc + 28, 84);
                chunk<true >(xr, wv, acc + 42, 98);
            }
        }
    }

    // store y (bf16) + per-lane (=per-co) stats
    __hip_bfloat16* yr = y + (((size_t)n*OHH + oh)*OWW + h*56)*64 + lane;
    float ssum = 0.f, ssq = 0.f;
    #pragma unroll
    for (int px = 0; px < 56; ++px) {
        float v = acc[px];
        ssum += v; ssq += v*v;
        yr[(size_t)px*64] = __float2bfloat16(v);
    }

    __shared__ float red[2][4][64];
    red[0][wid][lane] = ssum;
    red[1][wid][lane] = ssq;
    __syncthreads();
    if (wid == 0) {
        float s = red[0][0][lane] + red[0][1][lane] + red[0][2][lane] + red[0][3][lane];
        float q = red[1][0][lane] + red[1][1][lane] + red[1][2][lane] + red[1][3][lane];
        atomicAdd(&stats[lane*2 + 0], s);
        atomicAdd(&stats[lane*2 + 1], q);
    }
}

// BN-affine + ReLU + maxpool3x3 s2 p1. lane = co -> coalesced y reads.
// grid = 16*56*56*64/256 = 12544 blocks.
__global__ __launch_bounds__(256)
void pool_fast(const __hip_bfloat16* __restrict__ y, const float* __restrict__ stats,
               const float* __restrict__ gamma, const float* __restrict__ beta,
               float* __restrict__ out, int b)
{
    int idx = blockIdx.x*256 + threadIdx.x;
    int co = idx & 63;
    int t  = idx >> 6;
    int pw = t % PWW; t /= PWW;
    int ph = t % PHH;
    int n  = t / PHH;

    float mean = stats[co*2 + 0] * (1.f/CNT);
    float var  = stats[co*2 + 1] * (1.f/CNT) - mean*mean;
    float inv  = rsqrtf(var + 1e-5f);
    float scale = gamma[co]*inv;
    float shift = beta[co] - mean*scale;

    float mx = -1e30f, mn = 1e30f;
    int h0 = 2*ph - 1, w0 = 2*pw - 1;
    #pragma unroll
    for (int dh = 0; dh < 3; ++dh) {
        int ih = h0 + dh;
        if ((unsigned)ih < (unsigned)OHH) {
            const __hip_bfloat16* row = y + ((size_t)n*OHH + ih)*OWW*64;
            #pragma unroll
            for (int dw = 0; dw < 3; ++dw) {
                int iw = w0 + dw;
                if ((unsigned)iw < (unsigned)OWW) {
                    float v = __bfloat162float(row[(size_t)iw*64 + co]);
                    mx = fmaxf(mx, v);
                    mn = fminf(mn, v);
                }
            }
        }
    }
    float v = (scale >= 0.f) ? mx : mn;   // affine monotonicity
    float r = fmaxf(fmaf(v, scale, shift), 0.f);
    out[(((size_t)n*NBR + b)*COUT + co)*(PHH*PWW) + (size_t)ph*PWW + pw] = r;
}

// ================= fallback path (tiny workspace) =================
__global__ __launch_bounds__(512)
void conv_bn_stats(const float* __restrict__ x, const float* __restrict__ w,
                   float* __restrict__ stats, int b)
{
    __shared__ float xs[CIN][7][232];
    int bid = blockIdx.x;
    int oh  = bid % OHH;
    int n   = bid / OHH;
    const float* xb = x + ((size_t)(n*NBR + b))*CIN*HIN*WIN;
    int ihb = oh*2 - 3;
    for (int idx = threadIdx.x; idx < CIN*7*230; idx += 512) {
        int ci = idx / (7*230);
        int r  = idx - ci*(7*230);
        int kh = r / 230;
        int c  = r - kh*230;
        int ih = ihb + kh, iw = c - 3;
        float v = 0.f;
        if ((unsigned)ih < (unsigned)HIN && (unsigned)iw < (unsigned)WIN)
            v = xb[(ci*HIN + ih)*WIN + iw];
        xs[ci][kh][c] = v;
    }
    __syncthreads();
    int wid  = __builtin_amdgcn_readfirstlane(threadIdx.x >> 6);
    int lane = threadIdx.x & 63;
    int co0  = wid * 8;
    const float* wb = w + ((size_t)b*COUT + co0)*147;
    float acc0[8], acc1[8];
    #pragma unroll
    for (int cc = 0; cc < 8; ++cc) { acc0[cc] = 0.f; acc1[cc] = 0.f; }
    int ow1 = lane + 64;
    for (int ci = 0; ci < CIN; ++ci)
        for (int kh = 0; kh < 7; ++kh) {
            float wr[8][7];
            #pragma unroll
            for (int cc = 0; cc < 8; ++cc)
                #pragma unroll
                for (int kw = 0; kw < 7; ++kw)
                    wr[cc][kw] = wb[cc*147 + ci*49 + kh*7 + kw];
            const float* xr = &xs[ci][kh][0];
            #pragma unroll
            for (int kw = 0; kw < 7; ++kw) {
                float xv0 = xr[lane*2 + kw];
                float xv1 = (ow1 < OWW) ? xr[ow1*2 + kw] : 0.f;
                #pragma unroll
                for (int cc = 0; cc < 8; ++cc) {
                    acc0[cc] = fmaf(xv0, wr[cc][kw], acc0[cc]);
                    acc1[cc] = fmaf(xv1, wr[cc][kw], acc1[cc]);
                }
            }
        }
    #pragma unroll
    for (int cc = 0; cc < 8; ++cc) {
        float s = acc0[cc] + acc1[cc];
        float q = acc0[cc]*acc0[cc] + acc1[cc]*acc1[cc];
        #pragma unroll
        for (int off = 32; off; off >>= 1) {
            s += __shfl_xor(s, off);
            q += __shfl_xor(q, off);
        }
        if (lane == 0) {
            atomicAdd(&stats[(co0+cc)*2 + 0], s);
            atomicAdd(&stats[(co0+cc)*2 + 1], q);
        }
    }
}

__global__ __launch_bounds__(256)
void pool_recompute(const float* __restrict__ x, const float* __restrict__ w,
                    const float* __restrict__ stats, const float* __restrict__ gamma,
                    const float* __restrict__ beta, float* __restrict__ out, int b)
{
    int idx = blockIdx.x*256 + threadIdx.x;
    int pw = idx % PWW;
    int t  = idx / PWW;
    int ph = t % PHH; t /= PHH;
    int co = t % COUT;
    int n  = t / COUT;
    float mean = stats[co*2 + 0] * (1.f/CNT);
    float var  = stats[co*2 + 1] * (1.f/CNT) - mean*mean;
    float inv  = rsqrtf(var + 1e-5f);
    float scale = gamma[co]*inv;
    float shift = beta[co] - mean*scale;
    const float* xb = x + ((size_t)(n*NBR + b))*CIN*HIN*WIN;
    const float* wb = w + ((size_t)b*COUT + co)*147;
    float mx = -1e30f, mn = 1e30f;
    for (int dh = 0; dh < 3; ++dh) {
        int oh = 2*ph - 1 + dh;
        if ((unsigned)oh >= (unsigned)OHH) continue;
        for (int dw = 0; dw < 3; ++dw) {
            int ow = 2*pw - 1 + dw;
            if ((unsigned)ow >= (unsigned)OWW) continue;
            float a = 0.f;
            for (int ci = 0; ci < CIN; ++ci)
                for (int kh = 0; kh < 7; ++kh) {
                    int ih = oh*2 - 3 + kh;
                    if ((unsigned)ih >= (unsigned)HIN) continue;
                    for (int kw = 0; kw < 7; ++kw) {
                        int iw = ow*2 - 3 + kw;
                        if ((unsigned)iw >= (unsigned)WIN) continue;
                        a = fmaf(xb[(ci*HIN + ih)*WIN + iw], wb[ci*49 + kh*7 + kw], a);
                    }
                }
            mx = fmaxf(mx, a);
            mn = fminf(mn, a);
        }
    }
    float v = (scale >= 0.f) ? mx : mn;
    out[(((size_t)n*NBR + b)*COUT + co)*(PHH*PWW) + (size_t)ph*PWW + pw] =
        fmaxf(fmaf(v, scale, shift), 0.f);
}

extern "C" void kernel_launch(void* const* d_in, const int* in_sizes, int n_in,
                              void* d_out, int out_size, void* d_ws, size_t ws_size,
                              hipStream_t stream) {
    const float* x     = (const float*)d_in[0];
    const float* w     = (const float*)d_in[1];
    const float* gamma = (const float*)d_in[2];
    const float* beta  = (const float*)d_in[3];
    float* out = (float*)d_out;

    // ws layout: [0,4K) stats (8 branches x 128 f32); [4K,~45K) wT; [64K, +25.7MB) y
    float* stats = (float*)d_ws;
    float* wT    = (float*)((char*)d_ws + 4096);
    __hip_bfloat16* y = (__hip_bfloat16*)((char*)d_ws + 65536);
    const size_t yBytes = (size_t)NBATCH*OHH*OWW*COUT*sizeof(__hip_bfloat16);
    bool fits = ws_size >= 65536 + yBytes;

    hipMemsetAsync(d_ws, 0, 512*2*sizeof(float), stream);

    for (int b = 0; b < NBR; ++b) {
        float* statsB = stats + b*128;
        if (fits) {
            wtrans<<<37, 256, 0, stream>>>(w, wT, b);
            conv_fast<<<896, 256, 0, stream>>>(x, wT, y, statsB, b);
            pool_fast<<<NBATCH*PHH*PWW*COUT/256, 256, 0, stream>>>(
                y, statsB, gamma + b*COUT, beta + b*COUT, out, b);
        } else {
            conv_bn_stats<<<NBATCH*OHH, 512, 0, stream>>>(x, w, statsB, b);
            pool_recompute<<<NBATCH*COUT*PHH*PWW/256, 256, 0, stream>>>(
                x, w, statsB, gamma + b*COUT, beta + b*COUT, out, b);
        }
    }
}